// Round 10
// baseline (146.953 us; speedup 1.0000x reference)
//
#include <hip/hip_runtime.h>
#include <hip/hip_bf16.h>

typedef unsigned short u16;
typedef unsigned int u32;
typedef __attribute__((ext_vector_type(8))) short bf16x8;
typedef __attribute__((ext_vector_type(4))) float f32x4;
typedef __attribute__((ext_vector_type(2))) float f32x2;
typedef __attribute__((ext_vector_type(4))) unsigned short u16x4;

#define T_TILES 8    // 16-row tiles per block
#define NBLK    1024 // 1024 * 8 * 16 = 131072 rows; up to 4 blocks/CU

// shared_exp = floor(log2(amax)) - 8 ; scale = 2^shared_exp (power of two)
__device__ __forceinline__ void block_scale(float amax, float& scale, float& inv_scale) {
    int be = (int)(__float_as_uint(amax) >> 23);   // biased exponent, amax >= 0
    be = be < 8 ? 8 : be;                          // tiny/zero blocks quantize to 0 anyway
    scale     = __uint_as_float((unsigned)(be - 8) << 23);   // 2^(be-135)
    inv_scale = __uint_as_float((unsigned)(262 - be) << 23); // 2^(135-be)
}

#if __has_builtin(__builtin_amdgcn_cvt_pk_fp8_f32) && __has_builtin(__builtin_amdgcn_cvt_pk_f32_fp8)
#define HAS_HW_FP8 1
#else
#define HAS_HW_FP8 0
#endif

#if !HAS_HW_FP8
// Fallback: exact bit-math e4m3 RNE (verified in round 0)
__device__ __forceinline__ float mx_e4m3(float x, float inv_scale, float scale) {
    float v  = x * inv_scale;
    float av = fabsf(v);
    int e = (int)(__float_as_uint(av) >> 23) - 127;
    e = e < -6 ? -6 : (e > 8 ? 8 : e);
    float qs = __uint_as_float((unsigned)(130 - e) << 23);
    float qm = __uint_as_float((unsigned)(124 + e) << 23);
    float q  = fminf(rintf(av * qs) * qm, 448.0f);
    return copysignf(q, v) * scale;
}
#endif

// Quantize 4 elems to e4m3 grid (RNE, saturate 448), return bf16 bits of value*scale.
__device__ __forceinline__ u16x4 quant4(float4 v, float inv, float sc) {
    u16x4 r;
#if HAS_HW_FP8
    float a = fminf(fmaxf(v.x * inv, -448.f), 448.f);
    float b = fminf(fmaxf(v.y * inv, -448.f), 448.f);
    float c = fminf(fmaxf(v.z * inv, -448.f), 448.f);
    float d = fminf(fmaxf(v.w * inv, -448.f), 448.f);
    int p = __builtin_amdgcn_cvt_pk_fp8_f32(a, b, 0, false);   // RNE f32->e4m3 (OCP)
    p     = __builtin_amdgcn_cvt_pk_fp8_f32(c, d, p, true);
    f32x2 lo = __builtin_amdgcn_cvt_pk_f32_fp8(p, false);      // exact e4m3->f32
    f32x2 hi = __builtin_amdgcn_cvt_pk_f32_fp8(p, true);
    r.x = (u16)(__float_as_uint(lo[0] * sc) >> 16);
    r.y = (u16)(__float_as_uint(lo[1] * sc) >> 16);
    r.z = (u16)(__float_as_uint(hi[0] * sc) >> 16);
    r.w = (u16)(__float_as_uint(hi[1] * sc) >> 16);
#else
    r.x = (u16)(__float_as_uint(mx_e4m3(v.x, inv, sc)) >> 16);
    r.y = (u16)(__float_as_uint(mx_e4m3(v.y, inv, sc)) >> 16);
    r.z = (u16)(__float_as_uint(mx_e4m3(v.z, inv, sc)) >> 16);
    r.w = (u16)(__float_as_uint(mx_e4m3(v.w, inv, sc)) >> 16);
#endif
    return r;
}

// Quantize 256x256 weight to bf16 fake-quant, stored TRANSPOSED: Bq[n*256+k].
__global__ void wq_kernel(const float* __restrict__ W, u16* __restrict__ Bq) {
    const int t  = blockIdx.x * blockDim.x + threadIdx.x;
    const int f  = t * 4;
    const int k  = f >> 8;
    const int n0 = f & 255;
    const float4 v = *(const float4*)(W + f);
    float am = fmaxf(fmaxf(fabsf(v.x), fabsf(v.y)), fmaxf(fabsf(v.z), fabsf(v.w)));
    am = fmaxf(am, __shfl_xor(am, 1));   // 8 lanes x 4 elems = one 32-elem MX block
    am = fmaxf(am, __shfl_xor(am, 2));
    am = fmaxf(am, __shfl_xor(am, 4));
    float sc, inv; block_scale(am, sc, inv);
    u16x4 q = quant4(v, inv, sc);
    Bq[(size_t)(n0 + 0) * 256 + k] = q.x;
    Bq[(size_t)(n0 + 1) * 256 + k] = q.y;
    Bq[(size_t)(n0 + 2) * 256 + k] = q.z;
    Bq[(size_t)(n0 + 3) * 256 + k] = q.w;
}

// R9 structure (register-staged X pipeline, Aq dbuf, one raw barrier/iter) with:
//  - B NOT pinned in registers (R9's VGPR=124 proved the compiler refused anyway);
//    instead 1-ahead prefetched loads from L2 inside the MFMA loop (R2 pattern).
//  - Freed registers spent on concurrency: 1024 blocks, launch_bounds(256,3)
//    -> 3-4 resident blocks/CU = 3-4 independent pipelines overlapping phases.
__global__ void __launch_bounds__(256, 3)
mx_gemm(const float* __restrict__ X, const u16* __restrict__ Bq,
        const float* __restrict__ bias, float* __restrict__ out)
{
    __shared__ u16 Aq[2][16 * 256];      // 2 x 8 KB bf16, XOR-swizzled
    const int tid = threadIdx.x;
    const int w   = tid >> 6;
    const int l   = tid & 63;
    const int lr  = l & 15;
    const int lg  = l >> 4;
    const size_t row00 = (size_t)blockIdx.x * (16 * T_TILES);
    const float* xbase = X + row00 * 256;

    const u16* bb = Bq + (size_t)(w * 64 + lr) * 256 + lg * 8;
    float4 bv[4];
    #pragma unroll
    for (int ct = 0; ct < 4; ++ct)
        bv[ct] = *(const float4*)(bias + w * 64 + ct * 16 + lg * 4);

    // ---- prologue: load tiles 0 and 1 into register buffers ----
    float4 xv[2][4];
    #pragma unroll
    for (int pt = 0; pt < 2; ++pt)
        #pragma unroll
        for (int j = 0; j < 4; ++j)
            xv[pt][j] = *(const float4*)(xbase + (size_t)(pt * 16 + w * 4 + j) * 256 + l * 4);

    #pragma unroll
    for (int t = 0; t < T_TILES; ++t) {
        // ---- quantize own 4 rows from registers -> swizzled bf16 Aq[t&1] ----
        {
            u16* aqb = &Aq[t & 1][0];
            #pragma unroll
            for (int j = 0; j < 4; ++j) {
                const int r = w * 4 + j;
                const float4 v = xv[t & 1][j];
                float am = fmaxf(fmaxf(fabsf(v.x), fabsf(v.y)), fmaxf(fabsf(v.z), fabsf(v.w)));
                am = fmaxf(am, __shfl_xor(am, 1));  // 8-lane group = one 32-elem MX block
                am = fmaxf(am, __shfl_xor(am, 2));
                am = fmaxf(am, __shfl_xor(am, 4));
                float sc, inv; block_scale(am, sc, inv);
                u16x4 q = quant4(v, inv, sc);
                char* dst = (char*)aqb + (((u32)(r * 512 + l * 8)) ^ ((u32)(r & 7) << 4));
                *(u16x4*)dst = q;
            }
        }

        // ---- refill the just-freed register buffer with tile t+2 ----
        if (t + 2 < T_TILES) {
            #pragma unroll
            for (int j = 0; j < 4; ++j)
                xv[t & 1][j] = *(const float4*)(xbase + (size_t)((t + 2) * 16 + w * 4 + j) * 256 + l * 4);
        }
        __builtin_amdgcn_sched_barrier(0);   // pin prefetch issue above the barrier

        // ---- ONE barrier: Aq visible to all waves; vmcnt stays in flight ----
        asm volatile("s_waitcnt lgkmcnt(0)" ::: "memory");
        __builtin_amdgcn_s_barrier();

        // ---- MFMA: af from swizzled Aq (1-ahead), B from L2 (1-ahead prefetch) ----
        const char* ab = (const char*)&Aq[t & 1][0];
        const u32 swz = (u32)(lr & 7) << 4;
        bf16x8 afc = *(const bf16x8*)(ab + (((u32)(lr * 512 + lg * 16)) ^ swz));
        bf16x8 bcur[4];
        #pragma unroll
        for (int ct = 0; ct < 4; ++ct)
            bcur[ct] = *(const bf16x8*)(bb + (size_t)ct * 4096);

        f32x4 acc[4] = {};
        #pragma unroll
        for (int ks = 0; ks < 8; ++ks) {
            bf16x8 afn;
            bf16x8 bnxt[4];
            if (ks < 7) {
                afn = *(const bf16x8*)(ab + (((u32)(lr * 512 + (ks + 1) * 64 + lg * 16)) ^ swz));
                #pragma unroll
                for (int ct = 0; ct < 4; ++ct)
                    bnxt[ct] = *(const bf16x8*)(bb + (size_t)ct * 4096 + (ks + 1) * 32);
            }
            __builtin_amdgcn_s_setprio(1);
            #pragma unroll
            for (int ct = 0; ct < 4; ++ct)
                acc[ct] = __builtin_amdgcn_mfma_f32_16x16x32_bf16(
                    bcur[ct], afc, acc[ct], 0, 0, 0);
            __builtin_amdgcn_s_setprio(0);
            if (ks < 7) {
                afc = afn;
                #pragma unroll
                for (int ct = 0; ct < 4; ++ct) bcur[ct] = bnxt[ct];
            }
        }

        // ---- stores: lane holds C[row=lr][col=w*64+ct*16+lg*4 ..+3] ----
        const size_t row0 = row00 + (size_t)t * 16;
        #pragma unroll
        for (int ct = 0; ct < 4; ++ct) {
            f32x4 o = acc[ct];
            o[0] += bv[ct].x; o[1] += bv[ct].y; o[2] += bv[ct].z; o[3] += bv[ct].w;
            *(f32x4*)(out + (row0 + lr) * 256 + w * 64 + ct * 16 + lg * 4) = o;
        }
        // WAR safety: MFMA(t)'s ds_reads complete before this wave reaches
        // barrier(t+1); quant(t+2) (the next writer of Aq[t&1]) runs only after
        // ALL waves passed barrier(t+1) -> max skew 1 iteration, safe.
    }
}

extern "C" void kernel_launch(void* const* d_in, const int* in_sizes, int n_in,
                              void* d_out, int out_size, void* d_ws, size_t ws_size,
                              hipStream_t stream) {
    const float* x    = (const float*)d_in[0];
    const float* wk   = (const float*)d_in[1];
    const float* bias = (const float*)d_in[2];
    float* out = (float*)d_out;
    u16* Bq    = (u16*)d_ws;                  // 256*256 bf16 = 128 KB scratch
    wq_kernel<<<64, 256, 0, stream>>>(wk, Bq);
    mx_gemm<<<NBLK, 256, 0, stream>>>(x, Bq, bias, out);
}

// Round 11
// 118.640 us; speedup vs baseline: 1.2386x; 1.2386x over previous
//
#include <hip/hip_runtime.h>
#include <hip/hip_bf16.h>

typedef unsigned short u16;
typedef unsigned int u32;
typedef __attribute__((ext_vector_type(8))) short bf16x8;
typedef __attribute__((ext_vector_type(4))) float f32x4;
typedef __attribute__((ext_vector_type(2))) float f32x2;
typedef __attribute__((ext_vector_type(4))) unsigned short u16x4;

#define STRIPS 4    // 16-row strips per wave
#define NBLK   256  // 256 blocks x 512 rows = 131072 rows; 1 block/CU (LDS-exclusive)

// shared_exp = floor(log2(amax)) - 8 ; scale = 2^shared_exp (power of two)
__device__ __forceinline__ void block_scale(float amax, float& scale, float& inv_scale) {
    int be = (int)(__float_as_uint(amax) >> 23);   // biased exponent, amax >= 0
    be = be < 8 ? 8 : be;                          // tiny/zero blocks quantize to 0 anyway
    scale     = __uint_as_float((unsigned)(be - 8) << 23);   // 2^(be-135)
    inv_scale = __uint_as_float((unsigned)(262 - be) << 23); // 2^(135-be)
}

#if __has_builtin(__builtin_amdgcn_cvt_pk_fp8_f32) && __has_builtin(__builtin_amdgcn_cvt_pk_f32_fp8)
#define HAS_HW_FP8 1
#else
#define HAS_HW_FP8 0
#endif

#if !HAS_HW_FP8
// Fallback: exact bit-math e4m3 RNE (verified in round 0)
__device__ __forceinline__ float mx_e4m3(float x, float inv_scale, float scale) {
    float v  = x * inv_scale;
    float av = fabsf(v);
    int e = (int)(__float_as_uint(av) >> 23) - 127;
    e = e < -6 ? -6 : (e > 8 ? 8 : e);
    float qs = __uint_as_float((unsigned)(130 - e) << 23);
    float qm = __uint_as_float((unsigned)(124 + e) << 23);
    float q  = fminf(rintf(av * qs) * qm, 448.0f);
    return copysignf(q, v) * scale;
}
#endif

// Quantize 4 elems to e4m3 grid (RNE, saturate 448), return bf16 bits of value*scale.
__device__ __forceinline__ u16x4 quant4(float4 v, float inv, float sc) {
    u16x4 r;
#if HAS_HW_FP8
    float a = fminf(fmaxf(v.x * inv, -448.f), 448.f);
    float b = fminf(fmaxf(v.y * inv, -448.f), 448.f);
    float c = fminf(fmaxf(v.z * inv, -448.f), 448.f);
    float d = fminf(fmaxf(v.w * inv, -448.f), 448.f);
    int p = __builtin_amdgcn_cvt_pk_fp8_f32(a, b, 0, false);   // RNE f32->e4m3 (OCP)
    p     = __builtin_amdgcn_cvt_pk_fp8_f32(c, d, p, true);
    f32x2 lo = __builtin_amdgcn_cvt_pk_f32_fp8(p, false);      // exact e4m3->f32
    f32x2 hi = __builtin_amdgcn_cvt_pk_f32_fp8(p, true);
    r.x = (u16)(__float_as_uint(lo[0] * sc) >> 16);
    r.y = (u16)(__float_as_uint(lo[1] * sc) >> 16);
    r.z = (u16)(__float_as_uint(hi[0] * sc) >> 16);
    r.w = (u16)(__float_as_uint(hi[1] * sc) >> 16);
#else
    r.x = (u16)(__float_as_uint(mx_e4m3(v.x, inv, sc)) >> 16);
    r.y = (u16)(__float_as_uint(mx_e4m3(v.y, inv, sc)) >> 16);
    r.z = (u16)(__float_as_uint(mx_e4m3(v.z, inv, sc)) >> 16);
    r.w = (u16)(__float_as_uint(mx_e4m3(v.w, inv, sc)) >> 16);
#endif
    return r;
}

// Quantize 256x256 weight to bf16 fake-quant, stored TRANSPOSED: Bq[n*256+k].
__global__ void wq_kernel(const float* __restrict__ W, u16* __restrict__ Bq) {
    const int t  = blockIdx.x * blockDim.x + threadIdx.x;
    const int f  = t * 4;
    const int k  = f >> 8;
    const int n0 = f & 255;
    const float4 v = *(const float4*)(W + f);
    float am = fmaxf(fmaxf(fabsf(v.x), fabsf(v.y)), fmaxf(fabsf(v.z), fabsf(v.w)));
    am = fmaxf(am, __shfl_xor(am, 1));   // 8 lanes x 4 elems = one 32-elem MX block
    am = fmaxf(am, __shfl_xor(am, 2));
    am = fmaxf(am, __shfl_xor(am, 4));
    float sc, inv; block_scale(am, sc, inv);
    u16x4 q = quant4(v, inv, sc);
    Bq[(size_t)(n0 + 0) * 256 + k] = q.x;
    Bq[(size_t)(n0 + 1) * 256 + k] = q.y;
    Bq[(size_t)(n0 + 2) * 256 + k] = q.z;
    Bq[(size_t)(n0 + 3) * 256 + k] = q.w;
}

// Barrier-free streaming GEMM:
//  - ONE block of 8 waves per CU; whole B (bf16 [n][k], 128 KB) staged into LDS
//    once (XOR-swizzled, reg-staged), ONE __syncthreads, then zero barriers.
//  - each wave独立 streams 64 rows (4 strips x 16): X loaded straight into MFMA
//    fragment layout (lane lr = row, k = ks*32+lg*8; R3-verified), quantized
//    in-register (amax = shfl_xor 16/32 across the 4 lg-lanes = one MX block),
//    MFMA vs LDS-resident B, f32x4 stores. Next strip's 16 loads issued before
//    quant -> 16 KB in flight per wave; 8 desync'd waves keep HBM continuously fed.
//  - acc initialized from bias fragments (free bias add).
__global__ void __launch_bounds__(512, 1)
mx_gemm(const float* __restrict__ X, const u16* __restrict__ Bq,
        const float* __restrict__ bias, float* __restrict__ out)
{
    __shared__ u16   Bs[256 * 256];   // 128 KB, rows XOR-swizzled by (row&7)<<4
    __shared__ float bs[256];         // bias
    const int tid = threadIdx.x;
    const int w   = tid >> 6;
    const int l   = tid & 63;
    const int lr  = l & 15;
    const int lg  = l >> 4;

    // ---- one-time prologue: B -> LDS swizzled; bias -> LDS ----
    #pragma unroll
    for (int i = 0; i < 16; ++i) {
        const u32 g = (u32)(tid + i * 512) * 16;        // linear byte offset in Bq
        const u32 d = g ^ (((g >> 9) & 7) << 4);        // XOR bits 4..6 by row&7
        *(bf16x8*)((char*)Bs + d) = *(const bf16x8*)((const char*)Bq + g);
    }
    if (tid < 256) bs[tid] = bias[tid];
    __syncthreads();                                    // the ONLY barrier

    // ---- wave-private streaming over 64 rows ----
    const size_t rowW = (size_t)blockIdx.x * 512 + (size_t)w * 64;
    const float* xp = X + (rowW + lr) * 256 + lg * 8;   // lane's base (row lr)
    const u32   swz = (u32)(lr & 7) << 4;
    const char* BsB = (const char*)Bs;

    float4 xv[2][16];
    #pragma unroll
    for (int kp = 0; kp < 8; ++kp) {                    // strip 0 loads
        xv[0][2 * kp]     = *(const float4*)(xp + kp * 32);
        xv[0][2 * kp + 1] = *(const float4*)(xp + kp * 32 + 4);
    }

    #pragma unroll
    for (int s = 0; s < STRIPS; ++s) {
        // ---- issue next strip's 16 loads (in flight under this strip's work) ----
        if (s + 1 < STRIPS) {
            const float* xn = xp + (size_t)(s + 1) * 16 * 256;
            #pragma unroll
            for (int kp = 0; kp < 8; ++kp) {
                xv[(s + 1) & 1][2 * kp]     = *(const float4*)(xn + kp * 32);
                xv[(s + 1) & 1][2 * kp + 1] = *(const float4*)(xn + kp * 32 + 4);
            }
        }
        __builtin_amdgcn_sched_barrier(0);   // pin load issue above compute

        // ---- quantize strip s in-register (per ks = one 32-k MX block/row) ----
        bf16x8 af[8];
        #pragma unroll
        for (int ks = 0; ks < 8; ++ks) {
            const float4 v0 = xv[s & 1][2 * ks], v1 = xv[s & 1][2 * ks + 1];
            float am = fmaxf(fmaxf(fabsf(v0.x), fabsf(v0.y)), fmaxf(fabsf(v0.z), fabsf(v0.w)));
            am = fmaxf(am, fmaxf(fmaxf(fabsf(v1.x), fabsf(v1.y)), fmaxf(fabsf(v1.z), fabsf(v1.w))));
            am = fmaxf(am, __shfl_xor(am, 16));   // other lg lanes, same row
            am = fmaxf(am, __shfl_xor(am, 32));
            float sc, inv; block_scale(am, sc, inv);
            const u16x4 q0 = quant4(v0, inv, sc);
            const u16x4 q1 = quant4(v1, inv, sc);
            bf16x8 a;
            a[0] = (short)q0.x; a[1] = (short)q0.y; a[2] = (short)q0.z; a[3] = (short)q0.w;
            a[4] = (short)q1.x; a[5] = (short)q1.y; a[6] = (short)q1.z; a[7] = (short)q1.w;
            af[ks] = a;
        }

        // ---- acc init = bias fragments (free bias add) ----
        f32x4 acc[16];
        #pragma unroll
        for (int ct = 0; ct < 16; ++ct)
            acc[ct] = *(const f32x4*)(bs + ct * 16 + lg * 4);

        // ---- MFMA: B fragments from LDS (conflict-free via swizzle) ----
        #pragma unroll
        for (int ks = 0; ks < 8; ++ks) {
            #pragma unroll
            for (int ct = 0; ct < 16; ++ct) {
                const u32 off = ((u32)((ct * 16 + lr) * 512 + ks * 64 + lg * 16)) ^ swz;
                const bf16x8 bf = *(const bf16x8*)(BsB + off);
                acc[ct] = __builtin_amdgcn_mfma_f32_16x16x32_bf16(bf, af[ks], acc[ct], 0, 0, 0);
            }
        }

        // ---- stores: lane lr = row, cols ct*16 + lg*4 .. +3 ----
        float* op = out + (rowW + (size_t)s * 16 + lr) * 256 + lg * 4;
        #pragma unroll
        for (int ct = 0; ct < 16; ++ct)
            *(f32x4*)(op + ct * 16) = acc[ct];
    }
}

extern "C" void kernel_launch(void* const* d_in, const int* in_sizes, int n_in,
                              void* d_out, int out_size, void* d_ws, size_t ws_size,
                              hipStream_t stream) {
    const float* x    = (const float*)d_in[0];
    const float* wk   = (const float*)d_in[1];
    const float* bias = (const float*)d_in[2];
    float* out = (float*)d_out;
    u16* Bq    = (u16*)d_ws;                  // 256*256 bf16 = 128 KB scratch
    wq_kernel<<<64, 256, 0, stream>>>(wk, Bq);
    mx_gemm<<<NBLK, 512, 0, stream>>>(x, Bq, bias, out);
}